// Round 15
// baseline (741.033 us; speedup 1.0000x reference)
//
#include <hip/hip_runtime.h>
#include <stdint.h>

// RecursiveLSTM: B=1024, T=96, H=50, num_pred=12.
// ROUND-15 = ROUND-14 with the asm-constraint fix: hv (heavy-wave flag) is
// wave-uniform but NOT block-uniform, so "s" constraint was illegal; now
// passed as VGPR + hoisted via v_readfirstlane_b32 s23 once.
// BLOCK-PER-SEQUENCE, 256 threads (4 waves), LANE-PER-GATE.
// r8-r13: wave-per-sequence pinned at ~500us by serial recurrence tail at
// 1 wave/SIMD (4 structures, identical idle). Here: 1024 blocks x 4 waves
// = 4096 waves = 4/SIMD; other blocks' waves hide each step's tail.
// Lane g<200 owns gate g: 52-wide fused row [bias, W_ih, W_hh[g][0..49]]
// in FIXED regs v[64:115]. h_ext=[1,xv,h0..h49] in LDS; 13 broadcast
// ds_read_b128 + 26 pk_fma per wave/step; branch-free unified activation.
// c/h-update + FC on ONE wave (rotated across blocks via (b>>8)&3).
// 2 barriers/step (+1 light). VGPR ~116 <= 128 -> 4 blocks/CU.

#define TLEN 96

#define GRP(WT,A0,A1,WP0,WP1,H0,H1,POST) \
    "s_waitcnt lgkmcnt(" WT ")\n\t" \
    "v_pk_fma_f32 v[" A0 "], v[" WP0 "], v[" H0 "], v[" A0 "]\n\t" \
    "v_pk_fma_f32 v[" A1 "], v[" WP1 "], v[" H1 "], v[" A1 "]\n\t" \
    POST
#define GRPM(WT,A0,A1,WP0,WP1,H0,H1,POST) \
    "s_waitcnt lgkmcnt(" WT ")\n\t" \
    "v_pk_mul_f32 v[" A0 "], v[" WP0 "], v[" H0 "]\n\t" \
    "v_pk_mul_f32 v[" A1 "], v[" WP1 "], v[" H1 "]\n\t" \
    POST

__global__ __attribute__((amdgpu_flat_work_group_size(256, 256),
                          amdgpu_waves_per_eu(4)))
void rec_lstm_kernel(const float* __restrict__ x,
                     const float* __restrict__ W_ih,
                     const float* __restrict__ W_hh,
                     const float* __restrict__ b_ih,
                     const float* __restrict__ b_hh,
                     const float* __restrict__ W_fc,
                     const float* __restrict__ b_fc,
                     const int*   __restrict__ num_pred,
                     float*       __restrict__ out)
{
    const int b   = blockIdx.x;
    const int tid = threadIdx.x;

    __shared__ __align__(16) float lds[380];     // 1520 B
    if (tid < TLEN) lds[268 + tid] = x[b * TLEN + tid];   // xbuf @ float 268
    const int NP = num_pred[0];
    __syncthreads();

    const int      g    = (tid < 200) ? tid : 199;        // gate id (clamped)
    const int      lane = tid & 63;
    const uint32_t lb   = (uint32_t)(uintptr_t)&lds[0];
    const uint32_t g200 = (uint32_t)g * 200u;             // W_hh row byte off
    const uint32_t g4   = (uint32_t)g * 4u;
    const uint32_t l4   = (uint32_t)lane * 4u;
    const uint32_t u4   = (uint32_t)((lane < 50) ? lane : 49) * 4u;
    const uint32_t gw   = lb + 272u + g4;                 // gate write addr
    const uint32_t hw   = lb + 8u + l4;                   // hn write (lane>=50 -> pad)
    const uint32_t gr   = lb + 272u + u4;                 // gates read base
    const float    actn = (g >= 100 && g < 150) ? 2.0f : 1.0f;
    const float    actm = actn * 1.44269504f;             // n*log2(e)
    // heavy wave (c/h-update + FC), rotated across co-resident blocks.
    // Wave-uniform (NOT block-uniform) -> must be VGPR; hoisted to SGPR
    // in-asm via readfirstlane.
    const uint32_t hv   = ((tid >> 6) == ((b >> 8) & 3)) ? 0u : 1u;

    asm volatile(
        // ================ once: consts + weight load ================
        "v_readfirstlane_b32 s23, %[hv]\n\t"              // wave-uniform flag
        "s_load_dword s25, %[bfcp], 0x0\n\t"
        "global_load_dword v64, %[g4], %[bih]\n\t"        // b_ih[g]
        "global_load_dword v5,  %[g4], %[bhh]\n\t"        // b_hh[g]
        "global_load_dword v65, %[g4], %[wih]\n\t"        // W_ih[g]
        "global_load_dword v46, %[u4], %[wfcp]\n\t"       // W_fc[u]
        "global_load_dwordx4 v[66:69],   %[g200], %[whh]\n\t"
        "global_load_dwordx4 v[70:73],   %[g200], %[whh] offset:16\n\t"
        "global_load_dwordx4 v[74:77],   %[g200], %[whh] offset:32\n\t"
        "global_load_dwordx4 v[78:81],   %[g200], %[whh] offset:48\n\t"
        "global_load_dwordx4 v[82:85],   %[g200], %[whh] offset:64\n\t"
        "global_load_dwordx4 v[86:89],   %[g200], %[whh] offset:80\n\t"
        "global_load_dwordx4 v[90:93],   %[g200], %[whh] offset:96\n\t"
        "global_load_dwordx4 v[94:97],   %[g200], %[whh] offset:112\n\t"
        "global_load_dwordx4 v[98:101],  %[g200], %[whh] offset:128\n\t"
        "global_load_dwordx4 v[102:105], %[g200], %[whh] offset:144\n\t"
        "global_load_dwordx4 v[106:109], %[g200], %[whh] offset:160\n\t"
        "global_load_dwordx4 v[110:113], %[g200], %[whh] offset:176\n\t"
        "global_load_dwordx2 v[114:115], %[g200], %[whh] offset:192\n\t"
        "s_waitcnt vmcnt(0) lgkmcnt(0)\n\t"
        "v_add_f32 v64, v64, v5\n\t"                      // bias = b_ih+b_hh
        "v_cmp_gt_u32 vcc, 200, %[l4]\n\t"                // lane < 50 ?
        "v_cndmask_b32 v46, 0, v46, vcc\n\t"              // wfc (else 0)
        "v_add_u32 v42, 0x430, %[lb]\n\t"                 // xa = &xbuf[0]
        "v_mov_b32 v44, 1.0\n\t"
        "ds_write_b32 %[lb], v44\n\t"                     // h_ext[0] = 1.0
        "s_mov_b32 s21, %[np]\n\t"
        // ================== pass loop ==================
        "4:\n\t"
        "s_cmp_lg_u32 s23, 0\n\t"
        "s_cbranch_scc1 40f\n\t"
        "v_mov_b32 v36, 0\n\t"                            // c = 0
        "v_mov_b32 v44, 0\n\t"
        "ds_write_b32 %[hw], v44\n\t"                     // h[lane] = 0 (pad ok)
        "ds_read_b32 v43, v42\n\t"                        // x[p]
        "s_waitcnt lgkmcnt(0)\n\t"
        "ds_write_b32 %[lb], v43 offset:4\n\t"            // h_ext[1] = xv(t=0)
        "40:\n\t"
        "s_waitcnt lgkmcnt(0)\n\t"
        "s_barrier\n\t"
        "ds_read_b128 v[0:3],   %[lb] offset:0\n\t"       // 7 staged slots
        "ds_read_b128 v[4:7],   %[lb] offset:16\n\t"
        "ds_read_b128 v[8:11],  %[lb] offset:32\n\t"
        "ds_read_b128 v[12:15], %[lb] offset:48\n\t"
        "ds_read_b128 v[16:19], %[lb] offset:64\n\t"
        "ds_read_b128 v[20:23], %[lb] offset:80\n\t"
        "ds_read_b128 v[24:27], %[lb] offset:96\n\t"
        "s_mov_b32 s20, 96\n\t"
        // ================== step loop ==================
        "3:\n\t"
        GRPM("6","28:29","30:31","64:65","66:67","0:1","2:3",
             "ds_read_b128 v[0:3], %[lb] offset:112\n\t")
        GRPM("6","32:33","34:35","68:69","70:71","4:5","6:7",
             "ds_read_b128 v[4:7], %[lb] offset:128\n\t")
        GRP("6","28:29","30:31","72:73","74:75","8:9","10:11",
             "ds_read_b128 v[8:11], %[lb] offset:144\n\t")
        GRP("6","32:33","34:35","76:77","78:79","12:13","14:15",
             "ds_read_b128 v[12:15], %[lb] offset:160\n\t")
        GRP("6","28:29","30:31","80:81","82:83","16:17","18:19",
             "ds_read_b128 v[16:19], %[lb] offset:176\n\t")
        GRP("6","32:33","34:35","84:85","86:87","20:21","22:23",
             "ds_read_b128 v[20:23], %[lb] offset:192\n\t")
        GRP("6","28:29","30:31","88:89","90:91","24:25","26:27","")
        GRP("5","32:33","34:35","92:93","94:95","0:1","2:3","")
        GRP("4","28:29","30:31","96:97","98:99","4:5","6:7","")
        GRP("3","32:33","34:35","100:101","102:103","8:9","10:11","")
        GRP("2","28:29","30:31","104:105","106:107","12:13","14:15","")
        GRP("1","32:33","34:35","108:109","110:111","16:17","18:19","")
        GRP("0","28:29","30:31","112:113","114:115","20:21","22:23","")
        // fold 4 acc pairs -> scalar a (v28)
        "v_pk_add_f32 v[28:29], v[28:29], v[30:31]\n\t"
        "v_pk_add_f32 v[32:33], v[32:33], v[34:35]\n\t"
        "v_pk_add_f32 v[28:29], v[28:29], v[32:33]\n\t"
        "v_add_f32 v28, v28, v29\n\t"
        // unified activation: a = 1 - n/(exp2(m*a)+1)
        "v_mul_f32 v29, %[actm], v28\n\t"
        "v_exp_f32 v29, v29\n\t"
        "s_nop 1\n\t"
        "v_add_f32 v29, 1.0, v29\n\t"
        "v_rcp_f32 v29, v29\n\t"
        "s_nop 1\n\t"
        "v_fma_f32 v29, %[actn], -v29, 1.0\n\t"
        "ds_write_b32 %[gw], v29\n\t"
        "s_waitcnt lgkmcnt(0)\n\t"
        "s_barrier\n\t"
        // ---- phase B: heavy wave only ----
        "s_cmp_lg_u32 s23, 0\n\t"
        "s_cbranch_scc1 5f\n\t"
        "ds_read_b32 v0, %[gr]\n\t"                       // sig(i)
        "ds_read_b32 v1, %[gr] offset:200\n\t"            // sig(f)
        "ds_read_b32 v2, %[gr] offset:400\n\t"            // tanh(g)
        "ds_read_b32 v3, %[gr] offset:600\n\t"            // sig(o)
        "ds_read_b32 v43, v42 offset:4\n\t"               // x(t+1)
        "s_waitcnt lgkmcnt(1)\n\t"
        "v_mul_f32 v44, v0, v2\n\t"
        "v_fma_f32 v36, v1, v36, v44\n\t"                 // c = f*c + i*g
        "v_mul_f32 v44, 0x4038aa3b, v36\n\t"              // 2*log2e*c
        "v_exp_f32 v44, v44\n\t"
        "s_nop 1\n\t"
        "v_add_f32 v44, 1.0, v44\n\t"
        "v_rcp_f32 v44, v44\n\t"
        "s_nop 1\n\t"
        "v_fma_f32 v44, -2.0, v44, 1.0\n\t"               // tanh(c)
        "v_mul_f32 v37, v3, v44\n\t"                      // hn
        "ds_write_b32 %[hw], v37\n\t"
        "s_waitcnt lgkmcnt(0)\n\t"
        "ds_write_b32 %[lb], v43 offset:4\n\t"            // h_ext[1] = x(t+1)
        "v_add_u32 v42, 4, v42\n\t"
        "5:\n\t"
        "s_waitcnt lgkmcnt(0)\n\t"
        "s_barrier\n\t"
        "ds_read_b128 v[0:3],   %[lb] offset:0\n\t"       // next step's slots
        "ds_read_b128 v[4:7],   %[lb] offset:16\n\t"
        "ds_read_b128 v[8:11],  %[lb] offset:32\n\t"
        "ds_read_b128 v[12:15], %[lb] offset:48\n\t"
        "ds_read_b128 v[16:19], %[lb] offset:64\n\t"
        "ds_read_b128 v[20:23], %[lb] offset:80\n\t"
        "ds_read_b128 v[24:27], %[lb] offset:96\n\t"
        "s_sub_u32 s20, s20, 1\n\t"
        "s_cmp_lg_u32 s20, 0\n\t"
        "s_cbranch_scc1 3b\n\t"
        // ================== FC head (heavy wave) ==================
        "s_cmp_lg_u32 s23, 0\n\t"
        "s_cbranch_scc1 6f\n\t"
        "v_mul_f32 v44, v37, v46\n\t"
        "s_nop 1\n\t"
        "ds_swizzle_b32 v45, v44 offset:0x041F\n\t"
        "s_waitcnt lgkmcnt(0)\n\t"
        "v_add_f32 v44, v44, v45\n\t"
        "ds_swizzle_b32 v45, v44 offset:0x081F\n\t"
        "s_waitcnt lgkmcnt(0)\n\t"
        "v_add_f32 v44, v44, v45\n\t"
        "ds_swizzle_b32 v45, v44 offset:0x101F\n\t"
        "s_waitcnt lgkmcnt(0)\n\t"
        "v_add_f32 v44, v44, v45\n\t"
        "ds_swizzle_b32 v45, v44 offset:0x201F\n\t"
        "s_waitcnt lgkmcnt(0)\n\t"
        "v_add_f32 v44, v44, v45\n\t"
        "ds_swizzle_b32 v45, v44 offset:0x401F\n\t"
        "s_waitcnt lgkmcnt(0)\n\t"
        "v_add_f32 v44, v44, v45\n\t"
        "s_nop 1\n\t"
        "v_readlane_b32 s26, v44, 0\n\t"
        "v_readlane_b32 s27, v44, 32\n\t"
        "s_nop 4\n\t"
        "v_mov_b32 v45, s26\n\t"
        "v_add_f32 v45, s27, v45\n\t"
        "v_add_f32 v45, s25, v45\n\t"
        "ds_write_b32 v42, v45\n\t"                       // pred -> xbuf[96+p]
        "v_add_u32 v42, 0xfffffe84, v42\n\t"              // xa -> &xbuf[p+1]
        "6:\n\t"
        "s_waitcnt lgkmcnt(0)\n\t"
        "s_barrier\n\t"
        "s_sub_u32 s21, s21, 1\n\t"
        "s_cmp_lg_u32 s21, 0\n\t"
        "s_cbranch_scc1 4b\n\t"
        :
        : [lb] "v"(lb), [g200] "v"(g200), [g4] "v"(g4), [u4] "v"(u4),
          [l4] "v"(l4), [gw] "v"(gw), [hw] "v"(hw), [gr] "v"(gr),
          [actm] "v"(actm), [actn] "v"(actn),
          [hv] "v"(hv), [np] "s"(NP),
          [whh] "s"(W_hh), [bih] "s"(b_ih), [bhh] "s"(b_hh),
          [wih] "s"(W_ih), [wfcp] "s"(W_fc), [bfcp] "s"(b_fc)
        : "memory", "scc", "vcc", "s20", "s21", "s23", "s25", "s26", "s27",
          "v0","v1","v2","v3","v4","v5","v6","v7","v8","v9","v10","v11",
          "v12","v13","v14","v15","v16","v17","v18","v19","v20","v21",
          "v22","v23","v24","v25","v26","v27","v28","v29","v30","v31",
          "v32","v33","v34","v35","v36","v37","v42","v43","v44","v45","v46",
          "v64","v65","v66","v67","v68","v69","v70","v71","v72","v73",
          "v74","v75","v76","v77","v78","v79","v80","v81","v82","v83",
          "v84","v85","v86","v87","v88","v89","v90","v91","v92","v93",
          "v94","v95","v96","v97","v98","v99","v100","v101","v102","v103",
          "v104","v105","v106","v107","v108","v109","v110","v111","v112",
          "v113","v114","v115");

    if (tid < NP) out[b * NP + tid] = lds[364 + tid];     // xbuf[96+p]
}

extern "C" void kernel_launch(void* const* d_in, const int* in_sizes, int n_in,
                              void* d_out, int out_size, void* d_ws, size_t ws_size,
                              hipStream_t stream)
{
    const float* x    = (const float*)d_in[0];
    const float* W_ih = (const float*)d_in[1];
    const float* W_hh = (const float*)d_in[2];
    const float* b_ih = (const float*)d_in[3];
    const float* b_hh = (const float*)d_in[4];
    const float* W_fc = (const float*)d_in[5];
    const float* b_fc = (const float*)d_in[6];
    const int*   np   = (const int*)d_in[7];
    float* out = (float*)d_out;

    const int B = in_sizes[0] / TLEN;   // 1024
    rec_lstm_kernel<<<B, 256, 0, stream>>>(x, W_ih, W_hh, b_ih, b_hh,
                                           W_fc, b_fc, np, out);
}

// Round 17
// 448.725 us; speedup vs baseline: 1.6514x; 1.6514x over previous
//
#include <hip/hip_runtime.h>
#include <stdint.h>

// RecursiveLSTM: B=1024, T=96, H=50, num_pred=12.
// ROUND-17 = ROUND-16 with the register-budget fix: waves_per_eu(2) caps
// waves at 256 VGPR; r16 clobbered all 256 -> "requires more registers
// than available". Now: 4-slot staging (v0-15) + compact state (v16-34)
// + weights v48-255 = 243 clobbered, leaving v35-47 for the compiler.
//
// CONCURRENT-PASS WAVES: block = 1 sequence, 128 threads = 2 self-
// contained waves; wave w runs passes w, w+2, ... (6 each). Each wave =
// r13 single-chain body (weights in fixed regs, fused bias/W_ih pair-0).
// 2048 waves = 2/SIMD: the SIMD's wave interleaving hides the ~430cyc/step
// serial tail+LDS-turnaround that pinned r8-r13 at ~500us (1 wave/SIMD,
// nothing to interleave) -- and avoids r15's failure (gate-split waves,
// 4x LDS broadcast + 3 barriers around serial code).
// Pass handoff: pass q needs pred[q-1] only at t=94's prefetch of
// xbuf[q+95]; consumer spins on LDS flag[q] (flag[0] preset; deadlock-
// free by induction). One spin site per pass (s20==2).
//
// LDS floats: h_extA @0 (64), h_extB @64, xbuf @128 (112), flags @240.
// Regs: v0-15 slots S0-S3 | v16-23 accs | v24 c | v25 hn | v26 hb
// v27 hw | v28 xa | v29 wfc | v30 xv | v31/32 FC | v33 faddr | v34 tmp
// v35-47 FREE (compiler) | v48-255 weights (i/f/g/o; pair0=(bias,W_ih)).

#define TLEN 96

#define GRP(WT,IL,IH,FL,FH,GL,GH,OL,OH,BL,BH,POST) \
    "s_waitcnt lgkmcnt(" WT ")\n\t" \
    "v_pk_fma_f32 v[16:17], v[" IL "], v[" BL "], v[16:17]\n\t" \
    "v_pk_fma_f32 v[18:19], v[" FL "], v[" BL "], v[18:19]\n\t" \
    "v_pk_fma_f32 v[20:21], v[" GL "], v[" BL "], v[20:21]\n\t" \
    "v_pk_fma_f32 v[22:23], v[" OL "], v[" BL "], v[22:23]\n\t" \
    "v_pk_fma_f32 v[16:17], v[" IH "], v[" BH "], v[16:17]\n\t" \
    "v_pk_fma_f32 v[18:19], v[" FH "], v[" BH "], v[18:19]\n\t" \
    "v_pk_fma_f32 v[20:21], v[" GH "], v[" BH "], v[20:21]\n\t" \
    "v_pk_fma_f32 v[22:23], v[" OH "], v[" BH "], v[22:23]\n\t" \
    POST
#define GRPM(WT,IL,IH,FL,FH,GL,GH,OL,OH,BL,BH,POST) \
    "s_waitcnt lgkmcnt(" WT ")\n\t" \
    "v_pk_mul_f32 v[16:17], v[" IL "], v[" BL "]\n\t" \
    "v_pk_mul_f32 v[18:19], v[" FL "], v[" BL "]\n\t" \
    "v_pk_mul_f32 v[20:21], v[" GL "], v[" BL "]\n\t" \
    "v_pk_mul_f32 v[22:23], v[" OL "], v[" BL "]\n\t" \
    "v_pk_fma_f32 v[16:17], v[" IH "], v[" BH "], v[16:17]\n\t" \
    "v_pk_fma_f32 v[18:19], v[" FH "], v[" BH "], v[18:19]\n\t" \
    "v_pk_fma_f32 v[20:21], v[" GH "], v[" BH "], v[20:21]\n\t" \
    "v_pk_fma_f32 v[22:23], v[" OH "], v[" BH "], v[22:23]\n\t" \
    POST
#define GRPX(...)  GRP(__VA_ARGS__)
#define GRPMX(...) GRPM(__VA_ARGS__)

#define W0  "48:49","50:51","100:101","102:103","152:153","154:155","204:205","206:207"
#define W1  "52:53","54:55","104:105","106:107","156:157","158:159","208:209","210:211"
#define W2  "56:57","58:59","108:109","110:111","160:161","162:163","212:213","214:215"
#define W3  "60:61","62:63","112:113","114:115","164:165","166:167","216:217","218:219"
#define W4  "64:65","66:67","116:117","118:119","168:169","170:171","220:221","222:223"
#define W5  "68:69","70:71","120:121","122:123","172:173","174:175","224:225","226:227"
#define W6  "72:73","74:75","124:125","126:127","176:177","178:179","228:229","230:231"
#define W7  "76:77","78:79","128:129","130:131","180:181","182:183","232:233","234:235"
#define W8  "80:81","82:83","132:133","134:135","184:185","186:187","236:237","238:239"
#define W9  "84:85","86:87","136:137","138:139","188:189","190:191","240:241","242:243"
#define W10 "88:89","90:91","140:141","142:143","192:193","194:195","244:245","246:247"
#define W11 "92:93","94:95","144:145","146:147","196:197","198:199","248:249","250:251"
#define W12 "96:97","98:99","148:149","150:151","200:201","202:203","252:253","254:255"
#define SL0 "0:1","2:3"
#define SL1 "4:5","6:7"
#define SL2 "8:9","10:11"
#define SL3 "12:13","14:15"

__global__ __attribute__((amdgpu_flat_work_group_size(128, 128),
                          amdgpu_waves_per_eu(2)))
void rec_lstm_kernel(const float* __restrict__ x,
                     const float* __restrict__ W_ih,
                     const float* __restrict__ W_hh,
                     const float* __restrict__ b_ih,
                     const float* __restrict__ b_hh,
                     const float* __restrict__ W_fc,
                     const float* __restrict__ b_fc,
                     const int*   __restrict__ num_pred,
                     float*       __restrict__ out)
{
    const int b   = blockIdx.x;
    const int tid = threadIdx.x;

    __shared__ __align__(16) float lds[256];
    if (tid < TLEN) lds[128 + tid] = x[b * TLEN + tid];                // xbuf
    if (tid < 16)  ((uint32_t*)lds)[240 + tid] = (tid == 0) ? 1u : 0u; // flags
    const int NP = num_pred[0];
    __syncthreads();

    const int      wid = tid >> 6;                          // 0 or 1
    const uint32_t lb  = (uint32_t)(uintptr_t)&lds[0];
    const uint32_t hb  = lb + 256u * (uint32_t)wid;         // this wave's h_ext
    const uint32_t xa0 = lb + 512u + 4u * (uint32_t)wid;    // &xbuf[q0]
    const uint32_t fa0 = lb + 960u + 4u * (uint32_t)wid;    // &flag[q0]
    const int      np2 = NP >> 1;                           // passes per wave

    asm volatile(
        // ============ once: consts, lane calc, weight load ============
        "s_load_dword s25, %[bfcp], 0x0\n\t"
        "s_waitcnt lgkmcnt(0)\n\t"
        "v_mbcnt_lo_u32_b32 v0, -1, 0\n\t"
        "v_mbcnt_hi_u32_b32 v0, -1, v0\n\t"
        "s_mov_b32 s22, 49\n\t"
        "v_min_u32 v1, s22, v0\n\t"               // u = min(lane,49)
        "s_mov_b32 s22, 200\n\t"
        "v_mul_lo_u32 v2, s22, v1\n\t"            // i-row byte off
        "s_mov_b32 s22, 10000\n\t"
        "v_add_u32 v3, s22, v2\n\t"               // f-row
        "s_mov_b32 s22, 20000\n\t"
        "v_add_u32 v4, s22, v2\n\t"               // g-row
        "s_mov_b32 s22, 30000\n\t"
        "v_add_u32 v5, s22, v2\n\t"               // o-row
        "v_lshlrev_b32 v6, 2, v1\n\t"             // u*4
        "global_load_dword v48,  v6, %[bih]\n\t"
        "global_load_dword v100, v6, %[bih] offset:200\n\t"
        "global_load_dword v152, v6, %[bih] offset:400\n\t"
        "global_load_dword v204, v6, %[bih] offset:600\n\t"
        "global_load_dword v7,  v6, %[bhh]\n\t"
        "global_load_dword v8,  v6, %[bhh] offset:200\n\t"
        "global_load_dword v9,  v6, %[bhh] offset:400\n\t"
        "global_load_dword v10, v6, %[bhh] offset:600\n\t"
        "global_load_dword v49,  v6, %[wih]\n\t"
        "global_load_dword v101, v6, %[wih] offset:200\n\t"
        "global_load_dword v153, v6, %[wih] offset:400\n\t"
        "global_load_dword v205, v6, %[wih] offset:600\n\t"
        "global_load_dword v29, v6, %[wfcp]\n\t"
        "global_load_dwordx4 v[50:53], v2, %[whh]\n\t"
        "global_load_dwordx4 v[54:57], v2, %[whh] offset:16\n\t"
        "global_load_dwordx4 v[58:61], v2, %[whh] offset:32\n\t"
        "global_load_dwordx4 v[62:65], v2, %[whh] offset:48\n\t"
        "global_load_dwordx4 v[66:69], v2, %[whh] offset:64\n\t"
        "global_load_dwordx4 v[70:73], v2, %[whh] offset:80\n\t"
        "global_load_dwordx4 v[74:77], v2, %[whh] offset:96\n\t"
        "global_load_dwordx4 v[78:81], v2, %[whh] offset:112\n\t"
        "global_load_dwordx4 v[82:85], v2, %[whh] offset:128\n\t"
        "global_load_dwordx4 v[86:89], v2, %[whh] offset:144\n\t"
        "global_load_dwordx4 v[90:93], v2, %[whh] offset:160\n\t"
        "global_load_dwordx4 v[94:97], v2, %[whh] offset:176\n\t"
        "global_load_dwordx2 v[98:99], v2, %[whh] offset:192\n\t"
        "global_load_dwordx4 v[102:105], v3, %[whh]\n\t"
        "global_load_dwordx4 v[106:109], v3, %[whh] offset:16\n\t"
        "global_load_dwordx4 v[110:113], v3, %[whh] offset:32\n\t"
        "global_load_dwordx4 v[114:117], v3, %[whh] offset:48\n\t"
        "global_load_dwordx4 v[118:121], v3, %[whh] offset:64\n\t"
        "global_load_dwordx4 v[122:125], v3, %[whh] offset:80\n\t"
        "global_load_dwordx4 v[126:129], v3, %[whh] offset:96\n\t"
        "global_load_dwordx4 v[130:133], v3, %[whh] offset:112\n\t"
        "global_load_dwordx4 v[134:137], v3, %[whh] offset:128\n\t"
        "global_load_dwordx4 v[138:141], v3, %[whh] offset:144\n\t"
        "global_load_dwordx4 v[142:145], v3, %[whh] offset:160\n\t"
        "global_load_dwordx4 v[146:149], v3, %[whh] offset:176\n\t"
        "global_load_dwordx2 v[150:151], v3, %[whh] offset:192\n\t"
        "global_load_dwordx4 v[154:157], v4, %[whh]\n\t"
        "global_load_dwordx4 v[158:161], v4, %[whh] offset:16\n\t"
        "global_load_dwordx4 v[162:165], v4, %[whh] offset:32\n\t"
        "global_load_dwordx4 v[166:169], v4, %[whh] offset:48\n\t"
        "global_load_dwordx4 v[170:173], v4, %[whh] offset:64\n\t"
        "global_load_dwordx4 v[174:177], v4, %[whh] offset:80\n\t"
        "global_load_dwordx4 v[178:181], v4, %[whh] offset:96\n\t"
        "global_load_dwordx4 v[182:185], v4, %[whh] offset:112\n\t"
        "global_load_dwordx4 v[186:189], v4, %[whh] offset:128\n\t"
        "global_load_dwordx4 v[190:193], v4, %[whh] offset:144\n\t"
        "global_load_dwordx4 v[194:197], v4, %[whh] offset:160\n\t"
        "global_load_dwordx4 v[198:201], v4, %[whh] offset:176\n\t"
        "global_load_dwordx2 v[202:203], v4, %[whh] offset:192\n\t"
        "global_load_dwordx4 v[206:209], v5, %[whh]\n\t"
        "global_load_dwordx4 v[210:213], v5, %[whh] offset:16\n\t"
        "global_load_dwordx4 v[214:217], v5, %[whh] offset:32\n\t"
        "global_load_dwordx4 v[218:221], v5, %[whh] offset:48\n\t"
        "global_load_dwordx4 v[222:225], v5, %[whh] offset:64\n\t"
        "global_load_dwordx4 v[226:229], v5, %[whh] offset:80\n\t"
        "global_load_dwordx4 v[230:233], v5, %[whh] offset:96\n\t"
        "global_load_dwordx4 v[234:237], v5, %[whh] offset:112\n\t"
        "global_load_dwordx4 v[238:241], v5, %[whh] offset:128\n\t"
        "global_load_dwordx4 v[242:245], v5, %[whh] offset:144\n\t"
        "global_load_dwordx4 v[246:249], v5, %[whh] offset:160\n\t"
        "global_load_dwordx4 v[250:253], v5, %[whh] offset:176\n\t"
        "global_load_dwordx2 v[254:255], v5, %[whh] offset:192\n\t"
        "s_waitcnt vmcnt(0)\n\t"
        "v_add_f32 v48,  v48,  v7\n\t"            // b = b_ih + b_hh
        "v_add_f32 v100, v100, v8\n\t"
        "v_add_f32 v152, v152, v9\n\t"
        "v_add_f32 v204, v204, v10\n\t"
        "v_cmp_gt_u32 vcc, 50, v0\n\t"
        "v_cndmask_b32 v29, 0, v29, vcc\n\t"      // wfc (0 for idle lanes)
        "v_mov_b32 v26, %[hb]\n\t"                // h_ext base
        "v_lshl_add_u32 v27, v1, 2, v26\n\t"
        "v_add_u32 v27, 8, v27\n\t"               // hn write addr h_ext[2+u]
        "v_mov_b32 v28, %[xa0]\n\t"               // xa = &xbuf[q0]
        "v_mov_b32 v33, %[fa0]\n\t"               // faddr = &flag[q0]
        "v_mov_b32 v31, 1.0\n\t"
        "ds_write_b32 v26, v31\n\t"               // h_ext[0] = 1.0 (static)
        "s_mov_b32 s21, %[np2]\n\t"
        // ===================== pass loop =====================
        "4:\n\t"
        "v_mov_b32 v24, 0\n\t"                    // c = 0
        "v_mov_b32 v31, 0\n\t"
        "ds_write_b32 v27, v31\n\t"               // h[2+u] = 0
        "ds_read_b32 v30, v28\n\t"                // x(t=0) = xbuf[q]
        "s_waitcnt lgkmcnt(0)\n\t"
        "ds_write_b32 v26, v30 offset:4\n\t"      // h_ext[1] = xv(t=0)
        "ds_read_b128 v[0:3],   v26 offset:0\n\t" // stage S0..S3
        "ds_read_b128 v[4:7],   v26 offset:16\n\t"
        "ds_read_b128 v[8:11],  v26 offset:32\n\t"
        "ds_read_b128 v[12:15], v26 offset:48\n\t"
        "s_mov_b32 s20, 96\n\t"
        // ===================== step loop =====================
        "3:\n\t"
        // pred[q-1] gate: only t=94 (s20==2) prefetches xbuf[q+95]
        "s_cmp_lg_u32 s20, 2\n\t"
        "s_cbranch_scc1 31f\n\t"
        "30:\n\t"
        "ds_read_b32 v34, v33\n\t"                // flag[q]
        "s_waitcnt lgkmcnt(0)\n\t"
        "v_cmp_ne_u32 vcc, 0, v34\n\t"
        "s_cbranch_vccz 30b\n\t"
        "31:\n\t"
        "ds_read_b32 v30, v28 offset:4\n\t"       // xv(t+1)
        GRPMX("4", W0,  SL0, "ds_read_b128 v[0:3],   v26 offset:64\n\t")
        GRPX("4",  W1,  SL1, "ds_read_b128 v[4:7],   v26 offset:80\n\t")
        GRPX("4",  W2,  SL2, "ds_read_b128 v[8:11],  v26 offset:96\n\t")
        GRPX("4",  W3,  SL3, "ds_read_b128 v[12:15], v26 offset:112\n\t")
        GRPX("3",  W4,  SL0, "ds_read_b128 v[0:3],   v26 offset:128\n\t")
        GRPX("3",  W5,  SL1, "ds_read_b128 v[4:7],   v26 offset:144\n\t")
        GRPX("3",  W6,  SL2, "ds_read_b128 v[8:11],  v26 offset:160\n\t")
        GRPX("3",  W7,  SL3, "ds_read_b128 v[12:15], v26 offset:176\n\t")
        GRPX("3",  W8,  SL0, "ds_read_b128 v[0:3],   v26 offset:192\n\t")
        GRPX("3",  W9,  SL1, "")
        GRPX("2",  W10, SL2, "")
        GRPX("1",  W11, SL3, "")
        GRPX("0",  W12, SL0, "")
        // ---- fold + tail ----
        "v_add_f32 v16, v16, v17\n\t"             // ai
        "v_add_f32 v18, v18, v19\n\t"             // af
        "v_add_f32 v20, v20, v21\n\t"             // ag
        "v_add_f32 v22, v22, v23\n\t"             // ao
        "v_mul_f32 v17, 0xbfb8aa3b, v16\n\t"
        "v_mul_f32 v19, 0xbfb8aa3b, v18\n\t"
        "v_mul_f32 v21, 0x4038aa3b, v20\n\t"
        "v_mul_f32 v23, 0xbfb8aa3b, v22\n\t"
        "v_exp_f32 v17, v17\n\t"
        "v_exp_f32 v19, v19\n\t"
        "v_exp_f32 v21, v21\n\t"
        "v_exp_f32 v23, v23\n\t"
        "v_add_f32 v17, 1.0, v17\n\t"
        "v_add_f32 v19, 1.0, v19\n\t"
        "v_add_f32 v21, 1.0, v21\n\t"
        "v_add_f32 v23, 1.0, v23\n\t"
        "v_rcp_f32 v17, v17\n\t"                  // sig(i)
        "v_rcp_f32 v19, v19\n\t"                  // sig(f)
        "v_rcp_f32 v21, v21\n\t"                  // 1/(e^2g+1)
        "v_rcp_f32 v23, v23\n\t"                  // sig(o)
        "s_nop 1\n\t"
        "v_fma_f32 v21, -2.0, v21, 1.0\n\t"       // tanh(g)
        "v_mul_f32 v17, v17, v21\n\t"             // i*g
        "v_fma_f32 v24, v19, v24, v17\n\t"        // c = f*c + i*g
        "v_mul_f32 v19, 0x4038aa3b, v24\n\t"
        "v_exp_f32 v19, v19\n\t"
        "s_nop 1\n\t"
        "v_add_f32 v19, 1.0, v19\n\t"
        "v_rcp_f32 v19, v19\n\t"
        "s_nop 1\n\t"
        "v_fma_f32 v19, -2.0, v19, 1.0\n\t"       // tanh(c)
        "v_mul_f32 v25, v23, v19\n\t"             // hn = o * tanh(c)
        // ---- hn + x(t+1) writes, then next step's 4 staged reads ----
        "ds_write_b32 v27, v25\n\t"
        "ds_write_b32 v26, v30 offset:4\n\t"
        "ds_read_b128 v[0:3],   v26 offset:0\n\t"
        "ds_read_b128 v[4:7],   v26 offset:16\n\t"
        "ds_read_b128 v[8:11],  v26 offset:32\n\t"
        "ds_read_b128 v[12:15], v26 offset:48\n\t"
        "v_add_u32 v28, 4, v28\n\t"
        "s_sub_u32 s20, s20, 1\n\t"
        "s_cmp_lg_u32 s20, 0\n\t"
        "s_cbranch_scc1 3b\n\t"
        // ===================== FC head =====================
        "v_mul_f32 v31, v25, v29\n\t"
        "s_nop 1\n\t"
        "ds_swizzle_b32 v32, v31 offset:0x041F\n\t"
        "s_waitcnt lgkmcnt(0)\n\t"
        "v_add_f32 v31, v31, v32\n\t"
        "ds_swizzle_b32 v32, v31 offset:0x081F\n\t"
        "s_waitcnt lgkmcnt(0)\n\t"
        "v_add_f32 v31, v31, v32\n\t"
        "ds_swizzle_b32 v32, v31 offset:0x101F\n\t"
        "s_waitcnt lgkmcnt(0)\n\t"
        "v_add_f32 v31, v31, v32\n\t"
        "ds_swizzle_b32 v32, v31 offset:0x201F\n\t"
        "s_waitcnt lgkmcnt(0)\n\t"
        "v_add_f32 v31, v31, v32\n\t"
        "ds_swizzle_b32 v32, v31 offset:0x401F\n\t"
        "s_waitcnt lgkmcnt(0)\n\t"
        "v_add_f32 v31, v31, v32\n\t"
        "s_nop 1\n\t"
        "v_readlane_b32 s26, v31, 0\n\t"
        "v_readlane_b32 s27, v31, 32\n\t"
        "s_nop 4\n\t"
        "v_mov_b32 v32, s26\n\t"
        "v_add_f32 v32, s27, v32\n\t"
        "v_add_f32 v32, s25, v32\n\t"
        "ds_write_b32 v28, v32\n\t"               // pred[q] -> xbuf[96+q]
        "v_mov_b32 v34, 1.0\n\t"
        "ds_write_b32 v33, v34 offset:4\n\t"      // flag[q+1] = ready
        "s_waitcnt lgkmcnt(0)\n\t"
        "v_add_u32 v28, 0xfffffe88, v28\n\t"      // xa -> &xbuf[q+2]  (-376)
        "v_add_u32 v33, 8, v33\n\t"               // faddr -> &flag[q+2]
        "s_sub_u32 s21, s21, 1\n\t"
        "s_cmp_lg_u32 s21, 0\n\t"
        "s_cbranch_scc1 4b\n\t"
        :
        : [hb] "v"(hb), [xa0] "v"(xa0), [fa0] "v"(fa0), [np2] "s"(np2),
          [whh] "s"(W_hh), [wih] "s"(W_ih), [bih] "s"(b_ih), [bhh] "s"(b_hh),
          [wfcp] "s"(W_fc), [bfcp] "s"(b_fc)
        : "memory", "scc", "vcc", "s20", "s21", "s22", "s25", "s26", "s27",
          "v0","v1","v2","v3","v4","v5","v6","v7","v8","v9","v10","v11",
          "v12","v13","v14","v15","v16","v17","v18","v19","v20","v21","v22",
          "v23","v24","v25","v26","v27","v28","v29","v30","v31","v32","v33",
          "v34",
          "v48","v49","v50","v51","v52","v53","v54","v55","v56","v57","v58",
          "v59","v60","v61","v62","v63","v64","v65","v66","v67","v68","v69",
          "v70","v71","v72","v73","v74","v75","v76","v77","v78","v79","v80",
          "v81","v82","v83","v84","v85","v86","v87","v88","v89","v90","v91",
          "v92","v93","v94","v95","v96","v97","v98","v99","v100","v101",
          "v102","v103","v104","v105","v106","v107","v108","v109","v110",
          "v111","v112","v113","v114","v115","v116","v117","v118","v119",
          "v120","v121","v122","v123","v124","v125","v126","v127","v128",
          "v129","v130","v131","v132","v133","v134","v135","v136","v137",
          "v138","v139","v140","v141","v142","v143","v144","v145","v146",
          "v147","v148","v149","v150","v151","v152","v153","v154","v155",
          "v156","v157","v158","v159","v160","v161","v162","v163","v164",
          "v165","v166","v167","v168","v169","v170","v171","v172","v173",
          "v174","v175","v176","v177","v178","v179","v180","v181","v182",
          "v183","v184","v185","v186","v187","v188","v189","v190","v191",
          "v192","v193","v194","v195","v196","v197","v198","v199","v200",
          "v201","v202","v203","v204","v205","v206","v207","v208","v209",
          "v210","v211","v212","v213","v214","v215","v216","v217","v218",
          "v219","v220","v221","v222","v223","v224","v225","v226","v227",
          "v228","v229","v230","v231","v232","v233","v234","v235","v236",
          "v237","v238","v239","v240","v241","v242","v243","v244","v245",
          "v246","v247","v248","v249","v250","v251","v252","v253","v254",
          "v255");

    __syncthreads();   // both waves' preds committed
    if (tid < NP) out[b * NP + tid] = lds[224 + tid];   // xbuf[96+p]
}

extern "C" void kernel_launch(void* const* d_in, const int* in_sizes, int n_in,
                              void* d_out, int out_size, void* d_ws, size_t ws_size,
                              hipStream_t stream)
{
    const float* x    = (const float*)d_in[0];
    const float* W_ih = (const float*)d_in[1];
    const float* W_hh = (const float*)d_in[2];
    const float* b_ih = (const float*)d_in[3];
    const float* b_hh = (const float*)d_in[4];
    const float* W_fc = (const float*)d_in[5];
    const float* b_fc = (const float*)d_in[6];
    const int*   np   = (const int*)d_in[7];
    float* out = (float*)d_out;

    const int B = in_sizes[0] / TLEN;   // 1024
    rec_lstm_kernel<<<B, 128, 0, stream>>>(x, W_ih, W_hh, b_ih, b_hh,
                                           W_fc, b_fc, np, out);
}

// Round 19
// 438.352 us; speedup vs baseline: 1.6905x; 1.0237x over previous
//
#include <hip/hip_runtime.h>
#include <stdint.h>

// RecursiveLSTM: B=1024, T=96, H=50, num_pred=12.
// ROUND-19 = ROUND-18 RERUN (r18 was an infra failure: "container failed
// twice", no compile error; r6->r7 and r10->r11 precedent: resolves on
// unmodified rerun). Diff vs passing r17 is ONLY the anti-phase skew.
//
// r17 (437us, occ 21%, VALUBusy 74%) proved 2-waves/SIMD works but only
// hid HALF the idle: co-resident waves run identical code started
// simultaneously -> phase-locked -> serial tails coincide -> both stall
// together (idle 473/step-pair). Fix: each wave sleeps ((2b+wid)*7)&15 x
// s_sleep-1 (~0-960cyc, spans a full step) once before the pass loop,
// anti-phasing whichever pair the scheduler co-locates.
//
// CONCURRENT-PASS WAVES: block = 1 sequence, 128 threads = 2 self-
// contained waves; wave w runs passes w, w+2, ... (6 each). Weights in
// fixed regs v48-255 (fused bias/W_ih pair-0), 4-slot staging v0-15,
// state v16-34, v35-47 free for compiler (waves_per_eu(2) = 256-reg cap).
// Pass handoff: LDS flag[q] spin, checked once per pass at t=94.

#define TLEN 96

#define GRP(WT,IL,IH,FL,FH,GL,GH,OL,OH,BL,BH,POST) \
    "s_waitcnt lgkmcnt(" WT ")\n\t" \
    "v_pk_fma_f32 v[16:17], v[" IL "], v[" BL "], v[16:17]\n\t" \
    "v_pk_fma_f32 v[18:19], v[" FL "], v[" BL "], v[18:19]\n\t" \
    "v_pk_fma_f32 v[20:21], v[" GL "], v[" BL "], v[20:21]\n\t" \
    "v_pk_fma_f32 v[22:23], v[" OL "], v[" BL "], v[22:23]\n\t" \
    "v_pk_fma_f32 v[16:17], v[" IH "], v[" BH "], v[16:17]\n\t" \
    "v_pk_fma_f32 v[18:19], v[" FH "], v[" BH "], v[18:19]\n\t" \
    "v_pk_fma_f32 v[20:21], v[" GH "], v[" BH "], v[20:21]\n\t" \
    "v_pk_fma_f32 v[22:23], v[" OH "], v[" BH "], v[22:23]\n\t" \
    POST
#define GRPM(WT,IL,IH,FL,FH,GL,GH,OL,OH,BL,BH,POST) \
    "s_waitcnt lgkmcnt(" WT ")\n\t" \
    "v_pk_mul_f32 v[16:17], v[" IL "], v[" BL "]\n\t" \
    "v_pk_mul_f32 v[18:19], v[" FL "], v[" BL "]\n\t" \
    "v_pk_mul_f32 v[20:21], v[" GL "], v[" BL "]\n\t" \
    "v_pk_mul_f32 v[22:23], v[" OL "], v[" BL "]\n\t" \
    "v_pk_fma_f32 v[16:17], v[" IH "], v[" BH "], v[16:17]\n\t" \
    "v_pk_fma_f32 v[18:19], v[" FH "], v[" BH "], v[18:19]\n\t" \
    "v_pk_fma_f32 v[20:21], v[" GH "], v[" BH "], v[20:21]\n\t" \
    "v_pk_fma_f32 v[22:23], v[" OH "], v[" BH "], v[22:23]\n\t" \
    POST
#define GRPX(...)  GRP(__VA_ARGS__)
#define GRPMX(...) GRPM(__VA_ARGS__)

#define W0  "48:49","50:51","100:101","102:103","152:153","154:155","204:205","206:207"
#define W1  "52:53","54:55","104:105","106:107","156:157","158:159","208:209","210:211"
#define W2  "56:57","58:59","108:109","110:111","160:161","162:163","212:213","214:215"
#define W3  "60:61","62:63","112:113","114:115","164:165","166:167","216:217","218:219"
#define W4  "64:65","66:67","116:117","118:119","168:169","170:171","220:221","222:223"
#define W5  "68:69","70:71","120:121","122:123","172:173","174:175","224:225","226:227"
#define W6  "72:73","74:75","124:125","126:127","176:177","178:179","228:229","230:231"
#define W7  "76:77","78:79","128:129","130:131","180:181","182:183","232:233","234:235"
#define W8  "80:81","82:83","132:133","134:135","184:185","186:187","236:237","238:239"
#define W9  "84:85","86:87","136:137","138:139","188:189","190:191","240:241","242:243"
#define W10 "88:89","90:91","140:141","142:143","192:193","194:195","244:245","246:247"
#define W11 "92:93","94:95","144:145","146:147","196:197","198:199","248:249","250:251"
#define W12 "96:97","98:99","148:149","150:151","200:201","202:203","252:253","254:255"
#define SL0 "0:1","2:3"
#define SL1 "4:5","6:7"
#define SL2 "8:9","10:11"
#define SL3 "12:13","14:15"

__global__ __attribute__((amdgpu_flat_work_group_size(128, 128),
                          amdgpu_waves_per_eu(2)))
void rec_lstm_kernel(const float* __restrict__ x,
                     const float* __restrict__ W_ih,
                     const float* __restrict__ W_hh,
                     const float* __restrict__ b_ih,
                     const float* __restrict__ b_hh,
                     const float* __restrict__ W_fc,
                     const float* __restrict__ b_fc,
                     const int*   __restrict__ num_pred,
                     float*       __restrict__ out)
{
    const int b   = blockIdx.x;
    const int tid = threadIdx.x;

    __shared__ __align__(16) float lds[256];
    if (tid < TLEN) lds[128 + tid] = x[b * TLEN + tid];                // xbuf
    if (tid < 16)  ((uint32_t*)lds)[240 + tid] = (tid == 0) ? 1u : 0u; // flags
    const int NP = num_pred[0];
    __syncthreads();

    const int      wid = tid >> 6;                          // 0 or 1
    const uint32_t lb  = (uint32_t)(uintptr_t)&lds[0];
    const uint32_t hb  = lb + 256u * (uint32_t)wid;         // this wave's h_ext
    const uint32_t xa0 = lb + 512u + 4u * (uint32_t)wid;    // &xbuf[q0]
    const uint32_t fa0 = lb + 960u + 4u * (uint32_t)wid;    // &flag[q0]
    const int      np2 = NP >> 1;                           // passes per wave
    // anti-phase skew units (x ~64 cyc): decorrelates co-resident waves
    const uint32_t skw = ((2u * (uint32_t)b + (uint32_t)wid) * 7u) & 15u;

    asm volatile(
        // ============ once: consts, lane calc, weight load ============
        "s_load_dword s25, %[bfcp], 0x0\n\t"
        "s_waitcnt lgkmcnt(0)\n\t"
        "v_mbcnt_lo_u32_b32 v0, -1, 0\n\t"
        "v_mbcnt_hi_u32_b32 v0, -1, v0\n\t"
        "s_mov_b32 s22, 49\n\t"
        "v_min_u32 v1, s22, v0\n\t"               // u = min(lane,49)
        "s_mov_b32 s22, 200\n\t"
        "v_mul_lo_u32 v2, s22, v1\n\t"            // i-row byte off
        "s_mov_b32 s22, 10000\n\t"
        "v_add_u32 v3, s22, v2\n\t"               // f-row
        "s_mov_b32 s22, 20000\n\t"
        "v_add_u32 v4, s22, v2\n\t"               // g-row
        "s_mov_b32 s22, 30000\n\t"
        "v_add_u32 v5, s22, v2\n\t"               // o-row
        "v_lshlrev_b32 v6, 2, v1\n\t"             // u*4
        "global_load_dword v48,  v6, %[bih]\n\t"
        "global_load_dword v100, v6, %[bih] offset:200\n\t"
        "global_load_dword v152, v6, %[bih] offset:400\n\t"
        "global_load_dword v204, v6, %[bih] offset:600\n\t"
        "global_load_dword v7,  v6, %[bhh]\n\t"
        "global_load_dword v8,  v6, %[bhh] offset:200\n\t"
        "global_load_dword v9,  v6, %[bhh] offset:400\n\t"
        "global_load_dword v10, v6, %[bhh] offset:600\n\t"
        "global_load_dword v49,  v6, %[wih]\n\t"
        "global_load_dword v101, v6, %[wih] offset:200\n\t"
        "global_load_dword v153, v6, %[wih] offset:400\n\t"
        "global_load_dword v205, v6, %[wih] offset:600\n\t"
        "global_load_dword v29, v6, %[wfcp]\n\t"
        "global_load_dwordx4 v[50:53], v2, %[whh]\n\t"
        "global_load_dwordx4 v[54:57], v2, %[whh] offset:16\n\t"
        "global_load_dwordx4 v[58:61], v2, %[whh] offset:32\n\t"
        "global_load_dwordx4 v[62:65], v2, %[whh] offset:48\n\t"
        "global_load_dwordx4 v[66:69], v2, %[whh] offset:64\n\t"
        "global_load_dwordx4 v[70:73], v2, %[whh] offset:80\n\t"
        "global_load_dwordx4 v[74:77], v2, %[whh] offset:96\n\t"
        "global_load_dwordx4 v[78:81], v2, %[whh] offset:112\n\t"
        "global_load_dwordx4 v[82:85], v2, %[whh] offset:128\n\t"
        "global_load_dwordx4 v[86:89], v2, %[whh] offset:144\n\t"
        "global_load_dwordx4 v[90:93], v2, %[whh] offset:160\n\t"
        "global_load_dwordx4 v[94:97], v2, %[whh] offset:176\n\t"
        "global_load_dwordx2 v[98:99], v2, %[whh] offset:192\n\t"
        "global_load_dwordx4 v[102:105], v3, %[whh]\n\t"
        "global_load_dwordx4 v[106:109], v3, %[whh] offset:16\n\t"
        "global_load_dwordx4 v[110:113], v3, %[whh] offset:32\n\t"
        "global_load_dwordx4 v[114:117], v3, %[whh] offset:48\n\t"
        "global_load_dwordx4 v[118:121], v3, %[whh] offset:64\n\t"
        "global_load_dwordx4 v[122:125], v3, %[whh] offset:80\n\t"
        "global_load_dwordx4 v[126:129], v3, %[whh] offset:96\n\t"
        "global_load_dwordx4 v[130:133], v3, %[whh] offset:112\n\t"
        "global_load_dwordx4 v[134:137], v3, %[whh] offset:128\n\t"
        "global_load_dwordx4 v[138:141], v3, %[whh] offset:144\n\t"
        "global_load_dwordx4 v[142:145], v3, %[whh] offset:160\n\t"
        "global_load_dwordx4 v[146:149], v3, %[whh] offset:176\n\t"
        "global_load_dwordx2 v[150:151], v3, %[whh] offset:192\n\t"
        "global_load_dwordx4 v[154:157], v4, %[whh]\n\t"
        "global_load_dwordx4 v[158:161], v4, %[whh] offset:16\n\t"
        "global_load_dwordx4 v[162:165], v4, %[whh] offset:32\n\t"
        "global_load_dwordx4 v[166:169], v4, %[whh] offset:48\n\t"
        "global_load_dwordx4 v[170:173], v4, %[whh] offset:64\n\t"
        "global_load_dwordx4 v[174:177], v4, %[whh] offset:80\n\t"
        "global_load_dwordx4 v[178:181], v4, %[whh] offset:96\n\t"
        "global_load_dwordx4 v[182:185], v4, %[whh] offset:112\n\t"
        "global_load_dwordx4 v[186:189], v4, %[whh] offset:128\n\t"
        "global_load_dwordx4 v[190:193], v4, %[whh] offset:144\n\t"
        "global_load_dwordx4 v[194:197], v4, %[whh] offset:160\n\t"
        "global_load_dwordx4 v[198:201], v4, %[whh] offset:176\n\t"
        "global_load_dwordx2 v[202:203], v4, %[whh] offset:192\n\t"
        "global_load_dwordx4 v[206:209], v5, %[whh]\n\t"
        "global_load_dwordx4 v[210:213], v5, %[whh] offset:16\n\t"
        "global_load_dwordx4 v[214:217], v5, %[whh] offset:32\n\t"
        "global_load_dwordx4 v[218:221], v5, %[whh] offset:48\n\t"
        "global_load_dwordx4 v[222:225], v5, %[whh] offset:64\n\t"
        "global_load_dwordx4 v[226:229], v5, %[whh] offset:80\n\t"
        "global_load_dwordx4 v[230:233], v5, %[whh] offset:96\n\t"
        "global_load_dwordx4 v[234:237], v5, %[whh] offset:112\n\t"
        "global_load_dwordx4 v[238:241], v5, %[whh] offset:128\n\t"
        "global_load_dwordx4 v[242:245], v5, %[whh] offset:144\n\t"
        "global_load_dwordx4 v[246:249], v5, %[whh] offset:160\n\t"
        "global_load_dwordx4 v[250:253], v5, %[whh] offset:176\n\t"
        "global_load_dwordx2 v[254:255], v5, %[whh] offset:192\n\t"
        "s_waitcnt vmcnt(0)\n\t"
        "v_add_f32 v48,  v48,  v7\n\t"            // b = b_ih + b_hh
        "v_add_f32 v100, v100, v8\n\t"
        "v_add_f32 v152, v152, v9\n\t"
        "v_add_f32 v204, v204, v10\n\t"
        "v_cmp_gt_u32 vcc, 50, v0\n\t"
        "v_cndmask_b32 v29, 0, v29, vcc\n\t"      // wfc (0 for idle lanes)
        "v_mov_b32 v26, %[hb]\n\t"                // h_ext base
        "v_lshl_add_u32 v27, v1, 2, v26\n\t"
        "v_add_u32 v27, 8, v27\n\t"               // hn write addr h_ext[2+u]
        "v_mov_b32 v28, %[xa0]\n\t"               // xa = &xbuf[q0]
        "v_mov_b32 v33, %[fa0]\n\t"               // faddr = &flag[q0]
        "v_mov_b32 v31, 1.0\n\t"
        "ds_write_b32 v26, v31\n\t"               // h_ext[0] = 1.0 (static)
        "s_mov_b32 s21, %[np2]\n\t"
        // ---- anti-phase skew: sleep skw x ~64 cyc (one-time) ----
        "v_readfirstlane_b32 s24, %[skw]\n\t"
        "s_nop 3\n\t"
        "20:\n\t"
        "s_cmp_eq_u32 s24, 0\n\t"
        "s_cbranch_scc1 21f\n\t"
        "s_sleep 1\n\t"
        "s_sub_u32 s24, s24, 1\n\t"
        "s_branch 20b\n\t"
        "21:\n\t"
        // ===================== pass loop =====================
        "4:\n\t"
        "v_mov_b32 v24, 0\n\t"                    // c = 0
        "v_mov_b32 v31, 0\n\t"
        "ds_write_b32 v27, v31\n\t"               // h[2+u] = 0
        "ds_read_b32 v30, v28\n\t"                // x(t=0) = xbuf[q]
        "s_waitcnt lgkmcnt(0)\n\t"
        "ds_write_b32 v26, v30 offset:4\n\t"      // h_ext[1] = xv(t=0)
        "ds_read_b128 v[0:3],   v26 offset:0\n\t" // stage S0..S3
        "ds_read_b128 v[4:7],   v26 offset:16\n\t"
        "ds_read_b128 v[8:11],  v26 offset:32\n\t"
        "ds_read_b128 v[12:15], v26 offset:48\n\t"
        "s_mov_b32 s20, 96\n\t"
        // ===================== step loop =====================
        "3:\n\t"
        // pred[q-1] gate: only t=94 (s20==2) prefetches xbuf[q+95]
        "s_cmp_lg_u32 s20, 2\n\t"
        "s_cbranch_scc1 31f\n\t"
        "30:\n\t"
        "ds_read_b32 v34, v33\n\t"                // flag[q]
        "s_waitcnt lgkmcnt(0)\n\t"
        "v_cmp_ne_u32 vcc, 0, v34\n\t"
        "s_cbranch_vccz 30b\n\t"
        "31:\n\t"
        "ds_read_b32 v30, v28 offset:4\n\t"       // xv(t+1)
        GRPMX("4", W0,  SL0, "ds_read_b128 v[0:3],   v26 offset:64\n\t")
        GRPX("4",  W1,  SL1, "ds_read_b128 v[4:7],   v26 offset:80\n\t")
        GRPX("4",  W2,  SL2, "ds_read_b128 v[8:11],  v26 offset:96\n\t")
        GRPX("4",  W3,  SL3, "ds_read_b128 v[12:15], v26 offset:112\n\t")
        GRPX("3",  W4,  SL0, "ds_read_b128 v[0:3],   v26 offset:128\n\t")
        GRPX("3",  W5,  SL1, "ds_read_b128 v[4:7],   v26 offset:144\n\t")
        GRPX("3",  W6,  SL2, "ds_read_b128 v[8:11],  v26 offset:160\n\t")
        GRPX("3",  W7,  SL3, "ds_read_b128 v[12:15], v26 offset:176\n\t")
        GRPX("3",  W8,  SL0, "ds_read_b128 v[0:3],   v26 offset:192\n\t")
        GRPX("3",  W9,  SL1, "")
        GRPX("2",  W10, SL2, "")
        GRPX("1",  W11, SL3, "")
        GRPX("0",  W12, SL0, "")
        // ---- fold + tail ----
        "v_add_f32 v16, v16, v17\n\t"             // ai
        "v_add_f32 v18, v18, v19\n\t"             // af
        "v_add_f32 v20, v20, v21\n\t"             // ag
        "v_add_f32 v22, v22, v23\n\t"             // ao
        "v_mul_f32 v17, 0xbfb8aa3b, v16\n\t"
        "v_mul_f32 v19, 0xbfb8aa3b, v18\n\t"
        "v_mul_f32 v21, 0x4038aa3b, v20\n\t"
        "v_mul_f32 v23, 0xbfb8aa3b, v22\n\t"
        "v_exp_f32 v17, v17\n\t"
        "v_exp_f32 v19, v19\n\t"
        "v_exp_f32 v21, v21\n\t"
        "v_exp_f32 v23, v23\n\t"
        "v_add_f32 v17, 1.0, v17\n\t"
        "v_add_f32 v19, 1.0, v19\n\t"
        "v_add_f32 v21, 1.0, v21\n\t"
        "v_add_f32 v23, 1.0, v23\n\t"
        "v_rcp_f32 v17, v17\n\t"                  // sig(i)
        "v_rcp_f32 v19, v19\n\t"                  // sig(f)
        "v_rcp_f32 v21, v21\n\t"                  // 1/(e^2g+1)
        "v_rcp_f32 v23, v23\n\t"                  // sig(o)
        "s_nop 1\n\t"
        "v_fma_f32 v21, -2.0, v21, 1.0\n\t"       // tanh(g)
        "v_mul_f32 v17, v17, v21\n\t"             // i*g
        "v_fma_f32 v24, v19, v24, v17\n\t"        // c = f*c + i*g
        "v_mul_f32 v19, 0x4038aa3b, v24\n\t"
        "v_exp_f32 v19, v19\n\t"
        "s_nop 1\n\t"
        "v_add_f32 v19, 1.0, v19\n\t"
        "v_rcp_f32 v19, v19\n\t"
        "s_nop 1\n\t"
        "v_fma_f32 v19, -2.0, v19, 1.0\n\t"       // tanh(c)
        "v_mul_f32 v25, v23, v19\n\t"             // hn = o * tanh(c)
        // ---- hn + x(t+1) writes, then next step's 4 staged reads ----
        "ds_write_b32 v27, v25\n\t"
        "ds_write_b32 v26, v30 offset:4\n\t"
        "ds_read_b128 v[0:3],   v26 offset:0\n\t"
        "ds_read_b128 v[4:7],   v26 offset:16\n\t"
        "ds_read_b128 v[8:11],  v26 offset:32\n\t"
        "ds_read_b128 v[12:15], v26 offset:48\n\t"
        "v_add_u32 v28, 4, v28\n\t"
        "s_sub_u32 s20, s20, 1\n\t"
        "s_cmp_lg_u32 s20, 0\n\t"
        "s_cbranch_scc1 3b\n\t"
        // ===================== FC head =====================
        "v_mul_f32 v31, v25, v29\n\t"
        "s_nop 1\n\t"
        "ds_swizzle_b32 v32, v31 offset:0x041F\n\t"
        "s_waitcnt lgkmcnt(0)\n\t"
        "v_add_f32 v31, v31, v32\n\t"
        "ds_swizzle_b32 v32, v31 offset:0x081F\n\t"
        "s_waitcnt lgkmcnt(0)\n\t"
        "v_add_f32 v31, v31, v32\n\t"
        "ds_swizzle_b32 v32, v31 offset:0x101F\n\t"
        "s_waitcnt lgkmcnt(0)\n\t"
        "v_add_f32 v31, v31, v32\n\t"
        "ds_swizzle_b32 v32, v31 offset:0x201F\n\t"
        "s_waitcnt lgkmcnt(0)\n\t"
        "v_add_f32 v31, v31, v32\n\t"
        "ds_swizzle_b32 v32, v31 offset:0x401F\n\t"
        "s_waitcnt lgkmcnt(0)\n\t"
        "v_add_f32 v31, v31, v32\n\t"
        "s_nop 1\n\t"
        "v_readlane_b32 s26, v31, 0\n\t"
        "v_readlane_b32 s27, v31, 32\n\t"
        "s_nop 4\n\t"
        "v_mov_b32 v32, s26\n\t"
        "v_add_f32 v32, s27, v32\n\t"
        "v_add_f32 v32, s25, v32\n\t"
        "ds_write_b32 v28, v32\n\t"               // pred[q] -> xbuf[96+q]
        "v_mov_b32 v34, 1.0\n\t"
        "ds_write_b32 v33, v34 offset:4\n\t"      // flag[q+1] = ready
        "s_waitcnt lgkmcnt(0)\n\t"
        "v_add_u32 v28, 0xfffffe88, v28\n\t"      // xa -> &xbuf[q+2]  (-376)
        "v_add_u32 v33, 8, v33\n\t"               // faddr -> &flag[q+2]
        "s_sub_u32 s21, s21, 1\n\t"
        "s_cmp_lg_u32 s21, 0\n\t"
        "s_cbranch_scc1 4b\n\t"
        :
        : [hb] "v"(hb), [xa0] "v"(xa0), [fa0] "v"(fa0), [skw] "v"(skw),
          [np2] "s"(np2),
          [whh] "s"(W_hh), [wih] "s"(W_ih), [bih] "s"(b_ih), [bhh] "s"(b_hh),
          [wfcp] "s"(W_fc), [bfcp] "s"(b_fc)
        : "memory", "scc", "vcc", "s20", "s21", "s22", "s24", "s25", "s26",
          "s27",
          "v0","v1","v2","v3","v4","v5","v6","v7","v8","v9","v10","v11",
          "v12","v13","v14","v15","v16","v17","v18","v19","v20","v21","v22",
          "v23","v24","v25","v26","v27","v28","v29","v30","v31","v32","v33",
          "v34",
          "v48","v49","v50","v51","v52","v53","v54","v55","v56","v57","v58",
          "v59","v60","v61","v62","v63","v64","v65","v66","v67","v68","v69",
          "v70","v71","v72","v73","v74","v75","v76","v77","v78","v79","v80",
          "v81","v82","v83","v84","v85","v86","v87","v88","v89","v90","v91",
          "v92","v93","v94","v95","v96","v97","v98","v99","v100","v101",
          "v102","v103","v104","v105","v106","v107","v108","v109","v110",
          "v111","v112","v113","v114","v115","v116","v117","v118","v119",
          "v120","v121","v122","v123","v124","v125","v126","v127","v128",
          "v129","v130","v131","v132","v133","v134","v135","v136","v137",
          "v138","v139","v140","v141","v142","v143","v144","v145","v146",
          "v147","v148","v149","v150","v151","v152","v153","v154","v155",
          "v156","v157","v158","v159","v160","v161","v162","v163","v164",
          "v165","v166","v167","v168","v169","v170","v171","v172","v173",
          "v174","v175","v176","v177","v178","v179","v180","v181","v182",
          "v183","v184","v185","v186","v187","v188","v189","v190","v191",
          "v192","v193","v194","v195","v196","v197","v198","v199","v200",
          "v201","v202","v203","v204","v205","v206","v207","v208","v209",
          "v210","v211","v212","v213","v214","v215","v216","v217","v218",
          "v219","v220","v221","v222","v223","v224","v225","v226","v227",
          "v228","v229","v230","v231","v232","v233","v234","v235","v236",
          "v237","v238","v239","v240","v241","v242","v243","v244","v245",
          "v246","v247","v248","v249","v250","v251","v252","v253","v254",
          "v255");

    __syncthreads();   // both waves' preds committed
    if (tid < NP) out[b * NP + tid] = lds[224 + tid];   // xbuf[96+p]
}

extern "C" void kernel_launch(void* const* d_in, const int* in_sizes, int n_in,
                              void* d_out, int out_size, void* d_ws, size_t ws_size,
                              hipStream_t stream)
{
    const float* x    = (const float*)d_in[0];
    const float* W_ih = (const float*)d_in[1];
    const float* W_hh = (const float*)d_in[2];
    const float* b_ih = (const float*)d_in[3];
    const float* b_hh = (const float*)d_in[4];
    const float* W_fc = (const float*)d_in[5];
    const float* b_fc = (const float*)d_in[6];
    const int*   np   = (const int*)d_in[7];
    float* out = (float*)d_out;

    const int B = in_sizes[0] / TLEN;   // 1024
    rec_lstm_kernel<<<B, 128, 0, stream>>>(x, W_ih, W_hh, b_ih, b_hh,
                                           W_fc, b_fc, np, out);
}